// Round 1
// baseline (882.200 us; speedup 1.0000x reference)
//
#include <hip/hip_runtime.h>
#include <math.h>

// Problem constants (from reference)
#define T_DIM   8
#define N_NODES 100000
#define D_DIM   128
#define E_EDGES 50000
#define H0_DIM  64
#define H1_DIM  32
#define EPS_F   1e-8f

// One wave (64 lanes) per edge. Lane decomposition:
//   g = l>>4   : t-group (handles t=g and t=g+4)
//   m = (l>>2)&3 : head index (MS=4)
//   q = l&3    : quarter of D (32 elems each)
// Each lane accumulates 3 partials (ab,aa,bb) x 2 timesteps over its 32 d's.
// Reductions: 12 shfl (over q) + 8 shfl (over m) + 8 broadcast + 5 (pred) per edge.
__global__ __launch_bounds__(256) void fused_edge_cos_mlp(
    const int*   __restrict__ edge_list,  // (E,2) int32
    const float* __restrict__ z1,         // (T,N,D)
    const float* __restrict__ w1,         // (MS,D)
    const float* __restrict__ W0,         // (H0,T)
    const float* __restrict__ b0,         // (H0,)
    const float* __restrict__ W1,         // (H1,H0)
    const float* __restrict__ b1,         // (H1,)
    const float* __restrict__ Wp,         // (1,H1)
    const float* __restrict__ bp,         // (1,)
    float*       __restrict__ out)        // (E,)
{
    __shared__ float lds_h0[4 * 64];      // per-wave h0 slice

    const int tid  = threadIdx.x;
    const int wave = tid >> 6;
    const int l    = tid & 63;
    const int e    = blockIdx.x * 4 + wave;   // grid sized exactly: e < E

    const int g  = l >> 4;
    const int m  = (l >> 2) & 3;
    const int q  = l & 3;
    const int d0 = q * 32;

    const int src = edge_list[2 * e];
    const int dst = edge_list[2 * e + 1];

    // Squared weights for (head m, d in [d0, d0+32))  -- 8 x float4 in regs
    float4 wsq[8];
    {
        const float4* wp4 = reinterpret_cast<const float4*>(w1 + m * D_DIM + d0);
        #pragma unroll
        for (int j = 0; j < 8; ++j) {
            float4 w = wp4[j];
            wsq[j] = make_float4(w.x * w.x, w.y * w.y, w.z * w.z, w.w * w.w);
        }
    }

    float pab[2], paa[2], pbb[2];
    #pragma unroll
    for (int r = 0; r < 2; ++r) {
        const int t = g + 4 * r;
        const float4* arow = reinterpret_cast<const float4*>(
            z1 + ((size_t)t * N_NODES + src) * D_DIM + d0);
        const float4* brow = reinterpret_cast<const float4*>(
            z1 + ((size_t)t * N_NODES + dst) * D_DIM + d0);

        float s_ab = 0.f, s_aa = 0.f, s_bb = 0.f;
        #pragma unroll
        for (int j = 0; j < 8; ++j) {
            float4 a = arow[j];
            float4 b = brow[j];
            float4 w = wsq[j];
            s_ab = fmaf(a.x * b.x, w.x, s_ab);
            s_ab = fmaf(a.y * b.y, w.y, s_ab);
            s_ab = fmaf(a.z * b.z, w.z, s_ab);
            s_ab = fmaf(a.w * b.w, w.w, s_ab);
            s_aa = fmaf(a.x * a.x, w.x, s_aa);
            s_aa = fmaf(a.y * a.y, w.y, s_aa);
            s_aa = fmaf(a.z * a.z, w.z, s_aa);
            s_aa = fmaf(a.w * a.w, w.w, s_aa);
            s_bb = fmaf(b.x * b.x, w.x, s_bb);
            s_bb = fmaf(b.y * b.y, w.y, s_bb);
            s_bb = fmaf(b.z * b.z, w.z, s_bb);
            s_bb = fmaf(b.w * b.w, w.w, s_bb);
        }
        pab[r] = s_ab; paa[r] = s_aa; pbb[r] = s_bb;
    }

    // Reduce over q (masks 1,2): lanes with same (g,m) sum their quarters.
    #pragma unroll
    for (int r = 0; r < 2; ++r) {
        pab[r] += __shfl_xor(pab[r], 1); pab[r] += __shfl_xor(pab[r], 2);
        paa[r] += __shfl_xor(paa[r], 1); paa[r] += __shfl_xor(paa[r], 2);
        pbb[r] += __shfl_xor(pbb[r], 1); pbb[r] += __shfl_xor(pbb[r], 2);
    }

    // Per-head cosine, then mean over m (masks 4,8).
    float simr[2];
    #pragma unroll
    for (int r = 0; r < 2; ++r) {
        float na = sqrtf(paa[r]);
        float nb = sqrtf(pbb[r]);
        float c  = pab[r] / (fmaxf(na, EPS_F) * fmaxf(nb, EPS_F));
        c += __shfl_xor(c, 4);
        c += __shfl_xor(c, 8);
        simr[r] = 0.25f * c;   // sim for t = g (r=0), t = g+4 (r=1)
    }

    // Broadcast the 8 sims to all lanes (lane t*16 holds t-group t).
    float st[8];
    #pragma unroll
    for (int t = 0; t < 4; ++t) {
        st[t]     = __shfl(simr[0], t * 16);
        st[t + 4] = __shfl(simr[1], t * 16);
    }

    // Layer 0: lane j = l computes h0[j] = relu(sum_t st[t]*W0[j,t] + b0[j])
    {
        const float4* w0p = reinterpret_cast<const float4*>(W0 + l * T_DIM);
        float4 wa = w0p[0];
        float4 wb = w0p[1];
        float acc = b0[l];
        acc = fmaf(st[0], wa.x, acc); acc = fmaf(st[1], wa.y, acc);
        acc = fmaf(st[2], wa.z, acc); acc = fmaf(st[3], wa.w, acc);
        acc = fmaf(st[4], wb.x, acc); acc = fmaf(st[5], wb.y, acc);
        acc = fmaf(st[6], wb.z, acc); acc = fmaf(st[7], wb.w, acc);
        lds_h0[wave * 64 + l] = fmaxf(acc, 0.f);
    }
    __syncthreads();

    // Layer 1 + prediction: k = l&31 (both wave halves duplicate the work).
    {
        const int k = l & 31;
        const float4* w1p = reinterpret_cast<const float4*>(W1 + k * H0_DIM);
        const float4* h0p = reinterpret_cast<const float4*>(&lds_h0[wave * 64]);
        float acc = b1[k];
        #pragma unroll
        for (int jj = 0; jj < 16; ++jj) {
            float4 wv = w1p[jj];
            float4 hv = h0p[jj];   // same addr across lanes -> LDS broadcast
            acc = fmaf(wv.x, hv.x, acc);
            acc = fmaf(wv.y, hv.y, acc);
            acc = fmaf(wv.z, hv.z, acc);
            acc = fmaf(wv.w, hv.w, acc);
        }
        float p = fmaxf(acc, 0.f) * Wp[k];
        p += __shfl_xor(p, 1);
        p += __shfl_xor(p, 2);
        p += __shfl_xor(p, 4);
        p += __shfl_xor(p, 8);
        p += __shfl_xor(p, 16);
        if (l == 0) out[e] = p + bp[0];
    }
}

extern "C" void kernel_launch(void* const* d_in, const int* in_sizes, int n_in,
                              void* d_out, int out_size, void* d_ws, size_t ws_size,
                              hipStream_t stream) {
    const int*   edge_list = (const int*)  d_in[0];
    const float* z1        = (const float*)d_in[1];
    // d_in[2] = z2_trains  (unused by reference output)
    const float* w1        = (const float*)d_in[3];
    // d_in[4] = weight_vec2 (unused)
    const float* W0        = (const float*)d_in[5];
    const float* b0        = (const float*)d_in[6];
    const float* W1        = (const float*)d_in[7];
    const float* b1        = (const float*)d_in[8];
    const float* Wp        = (const float*)d_in[9];
    const float* bp        = (const float*)d_in[10];
    float*       out       = (float*)d_out;

    // 4 waves per block, 1 wave per edge. E = 50000 = 12500 * 4 exactly.
    dim3 block(256);
    dim3 grid(E_EDGES / 4);
    fused_edge_cos_mlp<<<grid, block, 0, stream>>>(
        edge_list, z1, w1, W0, b0, W1, b1, Wp, bp, out);
}

// Round 2
// 729.517 us; speedup vs baseline: 1.2093x; 1.2093x over previous
//
#include <hip/hip_runtime.h>
#include <math.h>

// Problem constants (from reference)
#define T_DIM   8
#define N_NODES 100000
#define D_DIM   128
#define E_EDGES 50000
#define H0_DIM  64
#define H1_DIM  32
#define EPS_F   1e-8f

// One wave (64 lanes) per edge. Lane decomposition:
//   t = l>>3 : timestep (T=8)
//   c = l&7  : 16-float chunk of D (8 chunks x 16 = 128)
// Each lane loads 4+4 float4 (src/dst rows) -- 8 independent VMEM instrs,
// all 64 lanes carry unique addresses (1 KB unique per instruction).
// Per lane: accumulate ab/aa/bb for all 4 heads (12 accumulators, weights
// from LDS broadcast). Reduce over c (shfl_xor 1,2,4), cosine per t-group,
// then fused 8->64->32->1 MLP per wave.
__global__ __launch_bounds__(256) void fused_edge_cos_mlp(
    const int*   __restrict__ edge_list,  // (E,2) int32
    const float* __restrict__ z1,         // (T,N,D)
    const float* __restrict__ w1,         // (MS,D)
    const float* __restrict__ W0,         // (H0,T)
    const float* __restrict__ b0,         // (H0,)
    const float* __restrict__ W1,         // (H1,H0)
    const float* __restrict__ b1,         // (H1,)
    const float* __restrict__ Wp,         // (1,H1)
    const float* __restrict__ bp,         // (1,)
    float*       __restrict__ out)        // (E,)
{
    __shared__ float wsq_lds[4 * D_DIM];  // squared head weights, 2 KB
    __shared__ float lds_h0[4 * H0_DIM];  // per-wave h0 slice

    const int tid  = threadIdx.x;
    const int wave = tid >> 6;
    const int l    = tid & 63;
    const int e    = blockIdx.x * 4 + wave;   // grid sized exactly: e < E

    // Stage squared weights once per block: 512 floats / 256 threads.
    {
        const float2* w2p = reinterpret_cast<const float2*>(w1);
        float2 w = w2p[tid];
        wsq_lds[2 * tid]     = w.x * w.x;
        wsq_lds[2 * tid + 1] = w.y * w.y;
    }

    const int t  = l >> 3;
    const int c  = l & 7;
    const int d0 = c * 16;

    const int src = edge_list[2 * e];
    const int dst = edge_list[2 * e + 1];

    // Issue all 8 row loads up front (independent, unique per lane).
    const float4* arow = reinterpret_cast<const float4*>(
        z1 + ((size_t)t * N_NODES + src) * D_DIM + d0);
    const float4* brow = reinterpret_cast<const float4*>(
        z1 + ((size_t)t * N_NODES + dst) * D_DIM + d0);
    float4 av[4], bv[4];
    #pragma unroll
    for (int j = 0; j < 4; ++j) av[j] = arow[j];
    #pragma unroll
    for (int j = 0; j < 4; ++j) bv[j] = brow[j];

    __syncthreads();   // wsq_lds ready (overlaps with load latency)

    // Accumulate 4 heads x {ab, aa, bb} over this lane's 16 d-elements.
    float s_ab[4], s_aa[4], s_bb[4];
    #pragma unroll
    for (int m = 0; m < 4; ++m) { s_ab[m] = 0.f; s_aa[m] = 0.f; s_bb[m] = 0.f; }

    #pragma unroll
    for (int m = 0; m < 4; ++m) {
        const float4* wq = reinterpret_cast<const float4*>(&wsq_lds[m * D_DIM + d0]);
        #pragma unroll
        for (int j = 0; j < 4; ++j) {
            float4 a = av[j];
            float4 b = bv[j];
            float4 w = wq[j];
            s_ab[m] = fmaf(a.x * b.x, w.x, s_ab[m]);
            s_ab[m] = fmaf(a.y * b.y, w.y, s_ab[m]);
            s_ab[m] = fmaf(a.z * b.z, w.z, s_ab[m]);
            s_ab[m] = fmaf(a.w * b.w, w.w, s_ab[m]);
            s_aa[m] = fmaf(a.x * a.x, w.x, s_aa[m]);
            s_aa[m] = fmaf(a.y * a.y, w.y, s_aa[m]);
            s_aa[m] = fmaf(a.z * a.z, w.z, s_aa[m]);
            s_aa[m] = fmaf(a.w * a.w, w.w, s_aa[m]);
            s_bb[m] = fmaf(b.x * b.x, w.x, s_bb[m]);
            s_bb[m] = fmaf(b.y * b.y, w.y, s_bb[m]);
            s_bb[m] = fmaf(b.z * b.z, w.z, s_bb[m]);
            s_bb[m] = fmaf(b.w * b.w, w.w, s_bb[m]);
        }
    }

    // Reduce over the 8 chunk-lanes (xor masks 1,2,4 within each t-group).
    #pragma unroll
    for (int m = 0; m < 4; ++m) {
        s_ab[m] += __shfl_xor(s_ab[m], 1);
        s_ab[m] += __shfl_xor(s_ab[m], 2);
        s_ab[m] += __shfl_xor(s_ab[m], 4);
        s_aa[m] += __shfl_xor(s_aa[m], 1);
        s_aa[m] += __shfl_xor(s_aa[m], 2);
        s_aa[m] += __shfl_xor(s_aa[m], 4);
        s_bb[m] += __shfl_xor(s_bb[m], 1);
        s_bb[m] += __shfl_xor(s_bb[m], 2);
        s_bb[m] += __shfl_xor(s_bb[m], 4);
    }

    // All 8 lanes of a t-group now hold the full sums: cosine mean over heads.
    float sim = 0.f;
    #pragma unroll
    for (int m = 0; m < 4; ++m) {
        float na = sqrtf(s_aa[m]);
        float nb = sqrtf(s_bb[m]);
        sim += s_ab[m] / (fmaxf(na, EPS_F) * fmaxf(nb, EPS_F));
    }
    sim *= 0.25f;

    // Broadcast the 8 per-t sims to all lanes (lane tt*8 holds t=tt).
    float st[8];
    #pragma unroll
    for (int tt = 0; tt < 8; ++tt) st[tt] = __shfl(sim, tt * 8);

    // Layer 0: lane j = l computes h0[j] = relu(sum_t st[t]*W0[j,t] + b0[j])
    {
        const float4* w0p = reinterpret_cast<const float4*>(W0 + l * T_DIM);
        float4 wa = w0p[0];
        float4 wb = w0p[1];
        float acc = b0[l];
        acc = fmaf(st[0], wa.x, acc); acc = fmaf(st[1], wa.y, acc);
        acc = fmaf(st[2], wa.z, acc); acc = fmaf(st[3], wa.w, acc);
        acc = fmaf(st[4], wb.x, acc); acc = fmaf(st[5], wb.y, acc);
        acc = fmaf(st[6], wb.z, acc); acc = fmaf(st[7], wb.w, acc);
        lds_h0[wave * H0_DIM + l] = fmaxf(acc, 0.f);
    }
    __syncthreads();

    // Layer 1 + prediction: k = l&31 (both wave halves duplicate the work).
    {
        const int k = l & 31;
        const float4* w1p = reinterpret_cast<const float4*>(W1 + k * H0_DIM);
        const float4* h0p = reinterpret_cast<const float4*>(&lds_h0[wave * H0_DIM]);
        float acc = b1[k];
        #pragma unroll
        for (int jj = 0; jj < 16; ++jj) {
            float4 wv = w1p[jj];
            float4 hv = h0p[jj];   // same addr across lanes -> LDS broadcast
            acc = fmaf(wv.x, hv.x, acc);
            acc = fmaf(wv.y, hv.y, acc);
            acc = fmaf(wv.z, hv.z, acc);
            acc = fmaf(wv.w, hv.w, acc);
        }
        float p = fmaxf(acc, 0.f) * Wp[k];
        p += __shfl_xor(p, 1);
        p += __shfl_xor(p, 2);
        p += __shfl_xor(p, 4);
        p += __shfl_xor(p, 8);
        p += __shfl_xor(p, 16);
        if (l == 0) out[e] = p + bp[0];
    }
}

extern "C" void kernel_launch(void* const* d_in, const int* in_sizes, int n_in,
                              void* d_out, int out_size, void* d_ws, size_t ws_size,
                              hipStream_t stream) {
    const int*   edge_list = (const int*)  d_in[0];
    const float* z1        = (const float*)d_in[1];
    // d_in[2] = z2_trains  (unused by reference output)
    const float* w1        = (const float*)d_in[3];
    // d_in[4] = weight_vec2 (unused)
    const float* W0        = (const float*)d_in[5];
    const float* b0        = (const float*)d_in[6];
    const float* W1        = (const float*)d_in[7];
    const float* b1        = (const float*)d_in[8];
    const float* Wp        = (const float*)d_in[9];
    const float* bp        = (const float*)d_in[10];
    float*       out       = (float*)d_out;

    // 4 waves per block, 1 wave per edge. E = 50000 = 12500 * 4 exactly.
    dim3 block(256);
    dim3 grid(E_EDGES / 4);
    fused_edge_cos_mlp<<<grid, block, 0, stream>>>(
        edge_list, z1, w1, W0, b0, W1, b1, Wp, bp, out);
}